// Round 3
// baseline (1260.024 us; speedup 1.0000x reference)
//
#include <hip/hip_runtime.h>

#define WW   320
#define HH   160
#define CIN  80
#define COUT 32
#define DD   48
#define NB   8
#define VP   84   // vol row pad (mult of 4 -> float4-aligned)

typedef __bf16 bf16x8 __attribute__((ext_vector_type(8)));
typedef float  float4v __attribute__((ext_vector_type(4)));
typedef float  float2v __attribute__((ext_vector_type(2)));

// One block per (b,h) row.
// Phase 1: preconv, images SEQUENTIAL (32 acc not 64), depth-16 pipelined
//          prefetch so 16-32 loads stay in flight per wave.
// Phase 2: banded A^T*B via mfma_f32_16x16x32_bf16 staged through LDS
//          vol[48][84], float4 coalesced stores in 4 passes of 80 cols.
__global__ __launch_bounds__(320, 2)
void vol_kernel(const float* __restrict__ inL, const float* __restrict__ inR,
                const float* __restrict__ gamma, const float* __restrict__ beta,
                const float* __restrict__ bnmean, const float* __restrict__ bnvar,
                const float* __restrict__ convw, const float* __restrict__ convb,
                float* __restrict__ out)
{
    __shared__ __bf16  fLs[WW * COUT];     // 20480 B
    __shared__ __bf16  fRs[WW * COUT];     // 20480 B
    __shared__ float   vol[DD * VP];       // 16128 B
    __shared__ float2v scsh[CIN];          //   640 B  (sc, sh)

    const int t = threadIdx.x;             // 0..319, == w
    const int b = blockIdx.x / HH;
    const int h = blockIdx.x % HH;
    const int w = t;
    const size_t HW = (size_t)HH * WW;

    // ---------- Phase 0: fold BN affine once ----------
    if (t < CIN) {
        float sc = gamma[t] * rsqrtf(bnvar[t] + 1e-5f);
        float2v v; v[0] = sc; v[1] = fmaf(-bnmean[t], sc, beta[t]);
        scsh[t] = v;
    }
    __syncthreads();

    // ---------- Phase 1: preconv, sequential images, pipelined loads ------
    for (int img = 0; img < 2; ++img) {
        const float* __restrict__ px =
            (img ? inR : inL) + ((size_t)b * CIN * HH + h) * WW + w;
        __bf16* f = img ? fRs : fLs;

        float acc[COUT];
        #pragma unroll
        for (int o = 0; o < COUT; ++o) acc[o] = convb[o];

        float xa[16], xb[16];
        #pragma unroll
        for (int u = 0; u < 16; ++u) xa[u] = px[(size_t)u * HW];   // batch 0

        #pragma unroll
        for (int cb = 0; cb < CIN; cb += 16) {
            if (cb + 16 < CIN) {               // prefetch next batch FIRST
                #pragma unroll
                for (int u = 0; u < 16; ++u)
                    xb[u] = px[(size_t)(cb + 16 + u) * HW];
            }
            #pragma unroll
            for (int u = 0; u < 16; ++u) {     // consume current batch
                int c = cb + u;
                float2v ss = scsh[c];          // ds_read_b64 broadcast
                float tv = fmaf(fmaxf(xa[u], 0.f), ss[0], ss[1]);
                #pragma unroll
                for (int o = 0; o < COUT; ++o)
                    acc[o] = fmaf(tv, convw[o * CIN + c], acc[o]);  // s_load wgt
            }
            if (cb + 16 < CIN) {
                #pragma unroll
                for (int u = 0; u < 16; ++u) xa[u] = xb[u];
            }
        }

        bf16x8 pk[4];
        #pragma unroll
        for (int o = 0; o < COUT; ++o) pk[o >> 3][o & 7] = (__bf16)acc[o];
        #pragma unroll
        for (int p = 0; p < 4; ++p)
            *(bf16x8*)(f + w * COUT + p * 8) = pk[p];    // ds_write_b128
    }
    __syncthreads();

    // ---------- Phase 2: banded A^T*B via MFMA ----------
    const int wave = t >> 6;
    const int lane = t & 63;
    const int ln15 = lane & 15;
    const int quad = lane >> 4;

    for (int pass = 0; pass < 4; ++pass) {
        for (int k = wave; k < 20; k += 5) {   // 4 (w-tile, lag) pairs per wave
            const int two = k >> 2;            // w-tile within pass: 0..4
            const int d   = k & 3;             // j-tile lag: 0..3
            const int tw  = pass * 5 + two;
            const int tj  = tw - d;
            if (tj < 0) continue;
            const int w0 = tw * 16, j0 = tj * 16;

            // A[m][k]: m=lane&15 (w), k=quad*8+j
            bf16x8 av = *(const bf16x8*)(fLs + (w0 + ln15) * COUT + quad * 8);
            // B[k][n]: n=lane&15 (j), k=quad*8+j
            bf16x8 bv = *(const bf16x8*)(fRs + (j0 + ln15) * COUT + quad * 8);

            float4v cz = {0.f, 0.f, 0.f, 0.f};
            float4v dv = __builtin_amdgcn_mfma_f32_16x16x32_bf16(av, bv, cz, 0, 0, 0);

            // D layout: row(m)=quad*4+r (w), col(n)=lane&15 (j); i = w - j
            #pragma unroll
            for (int r = 0; r < 4; ++r) {
                int row = quad * 4 + r;
                int i = 16 * d + row - ln15;
                if (i >= 0 && i < DD)
                    vol[i * VP + two * 16 + row] = dv[r] * (1.f / 32.f);
            }
        }
        __syncthreads();

        // coalesced float4 store of the 48 x 80 chunk; w<i band is 0
        for (int s = t; s < DD * 20; s += 320) {      // 3 iters
            int i  = s / 20;
            int q  = s - i * 20;
            int wg0 = pass * 80 + q * 4;
            float4v v = *(const float4v*)(vol + i * VP + q * 4);
            #pragma unroll
            for (int e = 0; e < 4; ++e)
                if (wg0 + e < i) v[e] = 0.f;
            *(float4v*)(out + ((size_t)(b * DD + i) * HH + h) * WW + wg0) = v;
        }
        __syncthreads();
    }
}

extern "C" void kernel_launch(void* const* d_in, const int* in_sizes, int n_in,
                              void* d_out, int out_size, void* d_ws, size_t ws_size,
                              hipStream_t stream) {
    const float* inL    = (const float*)d_in[0];
    const float* inR    = (const float*)d_in[1];
    const float* gamma  = (const float*)d_in[2];
    const float* beta   = (const float*)d_in[3];
    const float* bnmean = (const float*)d_in[4];
    const float* bnvar  = (const float*)d_in[5];
    const float* convw  = (const float*)d_in[6];
    const float* convb  = (const float*)d_in[7];
    float* out = (float*)d_out;

    dim3 grid(NB * HH);   // 1280 row-blocks
    dim3 block(320);
    vol_kernel<<<grid, block, 0, stream>>>(inL, inR, gamma, beta, bnmean, bnvar,
                                           convw, convb, out);
}

// Round 4
// 334.637 us; speedup vs baseline: 3.7653x; 3.7653x over previous
//
#include <hip/hip_runtime.h>

#define WW   320
#define HH   160
#define CIN  80
#define COUT 32
#define DD   48
#define NB   8
#define VP   84   // vol row pad (f32 words)

typedef __bf16 bf16x8 __attribute__((ext_vector_type(8)));
typedef __bf16 bf16x4 __attribute__((ext_vector_type(4)));
typedef float  float4v __attribute__((ext_vector_type(4)));

// One block per (b,h) row; t == w (320 threads, 5 waves).
// P0: fold BN: W'[o][c]=sc_c*W[o][c] -> A-frags in REGISTERS (once);
//     bias'_o = convb_o + sum_c sh_c*W[o][c] (parallel partial sums).
// P1 (per image): input staged in K-chunks of 32 through LDS xs2 (bf16,
//     relu only), MFMA [o=32 x w=320 x c=96] accumulating in regs; loads
//     for chunk k+1 issue before chunk k's MFMAs (deep MLP, tiny reg state).
//     D + bias' -> fLs/fRs bf16 [w][32], XOR-swizzled (conflict-free b128).
// P2: banded volume A^T*B (K=32) exactly as R1, swizzled reads, vol LDS
//     staging (union with xs2), float4 coalesced stores.
__global__ __launch_bounds__(320, 2)
void vol_kernel(const float* __restrict__ inL, const float* __restrict__ inR,
                const float* __restrict__ gamma, const float* __restrict__ beta,
                const float* __restrict__ bnmean, const float* __restrict__ bnvar,
                const float* __restrict__ convw, const float* __restrict__ convb,
                float* __restrict__ out)
{
    __shared__ __align__(16) __bf16 fLs[WW * COUT];       // 20480 B
    __shared__ __align__(16) __bf16 fRs[WW * COUT];       // 20480 B
    __shared__ __align__(16) char   uni[WW * COUT * 2];   // 20480 B: xs2 | vol
    __shared__ __align__(16) float  scs[96];              // sc (zero-pad 80..95)
    __shared__ float  shs[80];
    __shared__ float  biasp[32];
    __shared__ float  scratch[320];

    __bf16* xs2 = (__bf16*)uni;        // [320][32] bf16, swizzled
    float*  vol = (float*)uni;         // [48][84] f32 (phase 2 only)

    const int t = threadIdx.x;         // == w
    const int b = blockIdx.x / HH;
    const int h = blockIdx.x % HH;
    const size_t HW = (size_t)HH * WW;
    const int wave = t >> 6, lane = t & 63, ln15 = lane & 15, quad = lane >> 4;
    const int w = t;
    const int sw = (w >> 1) & 3;       // xor-swizzle key for this thread's row

    // ---------------- P0a: BN folds ----------------
    if (t < CIN) {
        float sc = gamma[t] * rsqrtf(bnvar[t] + 1e-5f);
        scs[t] = sc;
        shs[t] = fmaf(-bnmean[t], sc, beta[t]);
    } else if (t < 96) {
        scs[t] = 0.f;
    }
    __syncthreads();

    // ---------------- P0b: weight A-frags (regs) + bias partials ----------
    bf16x8 afr[2][3];   // [m-tile][k-chunk]; A[m=o][k=c] = W[o][c]*sc_c
    #pragma unroll
    for (int mt = 0; mt < 2; ++mt) {
        #pragma unroll
        for (int kk = 0; kk < 3; ++kk) {
            const int c0 = kk * 32 + quad * 8;
            bf16x8 a;
            if (c0 < CIN) {           // c0 multiple of 8; 80-c0 too -> no straddle
                const float* wp = convw + (mt * 16 + ln15) * CIN + c0;
                float4v w0 = *(const float4v*)wp;
                float4v w1 = *(const float4v*)(wp + 4);
                float4v s0 = *(const float4v*)(scs + c0);
                float4v s1 = *(const float4v*)(scs + c0 + 4);
                #pragma unroll
                for (int j = 0; j < 4; ++j) {
                    a[j]     = (__bf16)(w0[j] * s0[j]);
                    a[j + 4] = (__bf16)(w1[j] * s1[j]);
                }
            } else {
                #pragma unroll
                for (int j = 0; j < 8; ++j) a[j] = (__bf16)0.f;
            }
            afr[mt][kk] = a;
        }
    }
    {   // bias partials: thread (o=t&31, part=t>>5) does 8 FMAs
        const int o = t & 31, part = t >> 5;
        float p = 0.f;
        #pragma unroll
        for (int j = 0; j < 8; ++j) {
            int c = part * 8 + j;
            p = fmaf(shs[c], convw[o * CIN + c], p);
        }
        scratch[part * 32 + o] = p;
    }
    __syncthreads();
    if (t < 32) {
        float s = convb[t];
        #pragma unroll
        for (int pt = 0; pt < 10; ++pt) s += scratch[pt * 32 + t];
        biasp[t] = s;   // visible to all after next barrier (inside P1)
    }

    // ---------------- P1: preconv via MFMA, per image ----------------
    #pragma unroll 1
    for (int img = 0; img < 2; ++img) {
        const float* __restrict__ px =
            (img ? inR : inL) + ((size_t)b * CIN * HH + h) * WW + w;
        __bf16* f = img ? fRs : fLs;

        float4v acc[2][4];
        #pragma unroll
        for (int mt = 0; mt < 2; ++mt)
            #pragma unroll
            for (int nn = 0; nn < 4; ++nn) acc[mt][nn] = (float4v){0.f, 0.f, 0.f, 0.f};

        float y[32];
        // stage chunk 0
        #pragma unroll
        for (int u = 0; u < 32; ++u) y[u] = px[(size_t)u * HW];
        #pragma unroll
        for (int g = 0; g < 4; ++g) {
            bf16x8 pk;
            #pragma unroll
            for (int j = 0; j < 8; ++j) pk[j] = (__bf16)fmaxf(y[g * 8 + j], 0.f);
            *(bf16x8*)(xs2 + w * 32 + ((g ^ sw) << 3)) = pk;
        }
        __syncthreads();

        #pragma unroll
        for (int kk = 0; kk < 3; ++kk) {
            if (kk < 2) {               // prefetch chunk kk+1 (regs, overlaps MFMA)
                #pragma unroll
                for (int u = 0; u < 32; ++u) {
                    int c = (kk + 1) * 32 + u;
                    y[u] = (c < CIN) ? px[(size_t)c * HW] : 0.f;
                }
            }
            #pragma unroll
            for (int nn = 0; nn < 4; ++nn) {
                const int wr = (nn * 5 + wave) * 16 + ln15;   // n = w
                bf16x8 bv = *(const bf16x8*)(xs2 + wr * 32 +
                                             ((quad ^ ((wr >> 1) & 3)) << 3));
                acc[0][nn] = __builtin_amdgcn_mfma_f32_16x16x32_bf16(afr[0][kk], bv, acc[0][nn], 0, 0, 0);
                acc[1][nn] = __builtin_amdgcn_mfma_f32_16x16x32_bf16(afr[1][kk], bv, acc[1][nn], 0, 0, 0);
            }
            __syncthreads();            // all reads of xs2 done
            if (kk < 2) {
                #pragma unroll
                for (int g = 0; g < 4; ++g) {
                    bf16x8 pk;
                    #pragma unroll
                    for (int j = 0; j < 8; ++j) pk[j] = (__bf16)fmaxf(y[g * 8 + j], 0.f);
                    *(bf16x8*)(xs2 + w * 32 + ((g ^ sw) << 3)) = pk;
                }
                __syncthreads();        // staged for next iter
            }
        }

        // D (+bias) -> f bf16 [w][o], swizzled. D: row(m=o)=quad*4+r, col(n=w)=ln15
        #pragma unroll
        for (int nn = 0; nn < 4; ++nn) {
            const int wg  = (nn * 5 + wave) * 16 + ln15;
            const int swg = (wg >> 1) & 3;
            #pragma unroll
            for (int mt = 0; mt < 2; ++mt) {
                float4v bi = *(const float4v*)(biasp + mt * 16 + quad * 4);
                bf16x4 o4;
                #pragma unroll
                for (int r = 0; r < 4; ++r)
                    o4[r] = (__bf16)(acc[mt][nn][r] + bi[r]);
                const int g = 2 * mt + (quad >> 1);
                *(bf16x4*)(f + wg * 32 + ((g ^ swg) << 3) + (quad & 1) * 4) = o4;
            }
        }
    }
    __syncthreads();

    // ---------------- P2: banded volume via MFMA (as R1) ----------------
    for (int pass = 0; pass < 4; ++pass) {
        for (int k = wave; k < 20; k += 5) {
            const int two = k >> 2;            // w-tile within pass: 0..4
            const int d   = k & 3;             // j-tile lag: 0..3
            const int tw  = pass * 5 + two;
            const int tj  = tw - d;
            if (tj >= 0) {
                const int wr = tw * 16 + ln15;  // A row (w)
                const int jr = tj * 16 + ln15;  // B row (j)
                bf16x8 av = *(const bf16x8*)(fLs + wr * 32 +
                                             ((quad ^ ((wr >> 1) & 3)) << 3));
                bf16x8 bv = *(const bf16x8*)(fRs + jr * 32 +
                                             ((quad ^ ((jr >> 1) & 3)) << 3));
                float4v cz = {0.f, 0.f, 0.f, 0.f};
                float4v dv = __builtin_amdgcn_mfma_f32_16x16x32_bf16(av, bv, cz, 0, 0, 0);
                #pragma unroll
                for (int r = 0; r < 4; ++r) {
                    int row = quad * 4 + r;
                    int i = 16 * d + row - ln15;   // disparity
                    if (i >= 0 && i < DD)
                        vol[i * VP + two * 16 + row] = dv[r] * (1.f / 32.f);
                }
            }
        }
        __syncthreads();

        // coalesced float4 store of 48 x 80 chunk; w<i band forced to 0
        for (int s = t; s < DD * 20; s += 320) {
            int i = s / 20, q = s - i * 20;
            int wg0 = pass * 80 + q * 4;
            float4v v = *(const float4v*)(vol + i * VP + q * 4);
            #pragma unroll
            for (int e = 0; e < 4; ++e)
                if (wg0 + e < i) v[e] = 0.f;
            *(float4v*)(out + ((size_t)(b * DD + i) * HH + h) * WW + wg0) = v;
        }
        __syncthreads();
    }
}

extern "C" void kernel_launch(void* const* d_in, const int* in_sizes, int n_in,
                              void* d_out, int out_size, void* d_ws, size_t ws_size,
                              hipStream_t stream) {
    const float* inL    = (const float*)d_in[0];
    const float* inR    = (const float*)d_in[1];
    const float* gamma  = (const float*)d_in[2];
    const float* beta   = (const float*)d_in[3];
    const float* bnmean = (const float*)d_in[4];
    const float* bnvar  = (const float*)d_in[5];
    const float* convw  = (const float*)d_in[6];
    const float* convb  = (const float*)d_in[7];
    float* out = (float*)d_out;

    dim3 grid(NB * HH);   // 1280 row-blocks
    dim3 block(320);
    vol_kernel<<<grid, block, 0, stream>>>(inL, inR, gamma, beta, bnmean, bnvar,
                                           convw, convb, out);
}